// Round 5
// baseline (3059.227 us; speedup 1.0000x reference)
//
#include <hip/hip_runtime.h>
#include <hip/hip_fp16.h>

#define TT 30
#define BATCH 8192

typedef _Float16 f16x8v __attribute__((ext_vector_type(8)));
typedef float    f32x4v __attribute__((ext_vector_type(4)));
typedef unsigned int u32x4v __attribute__((ext_vector_type(4)));

__device__ __forceinline__ float sigf(float x) { return 1.0f / (1.0f + __expf(-x)); }

__device__ __forceinline__ f16x8v ldb16(const __half* p) {
    return __builtin_bit_cast(f16x8v, *(const u32x4v*)p);
}
__device__ __forceinline__ f32x4v mfma16(f16x8v a, f16x8v b, f32x4v c) {
    return __builtin_amdgcn_mfma_f32_16x16x32_f16(a, b, c, 0, 0, 0);
}

// ---------------------------------------------------------------------------
// x (B,T,126) fp32 -> x16 (B,T,128) f16, zero-padded cols 126..127
// ---------------------------------------------------------------------------
__global__ __launch_bounds__(256)
void x_to_f16(const float* __restrict__ x, __half* __restrict__ x16)
{
    const size_t i = (size_t)blockIdx.x * 256 + threadIdx.x;  // < B*T*128
    const int k = (int)(i & 127);
    const size_t bt = i >> 7;
    x16[i] = (k < 126) ? __float2half(x[bt * 126 + k]) : __half(0.0f);
}

// ---------------------------------------------------------------------------
// Pack LSTM weights into MFMA B-fragment order, streaming layout:
//   dst flat: [dir][wv WAVES][jh JH][kt KT][g 4][lane 64][jj 8]
// element = B[k][col], k = kt*32 + (lane>>4)*8 + jj (rows: W 0..DINP-1
// zero-padded past DINS, then Urec), col = g*U + wv*(U/WAVES) + jh*16 +
// (lane&15). Per (jh,kt) the 4 gate fragments are one contiguous 4 KB run.
// ---------------------------------------------------------------------------
template<int DINS, int DINP, int U, int WAVES>
__global__ __launch_bounds__(256)
void pack_b(const float* __restrict__ wf, const float* __restrict__ uf,
            const float* __restrict__ wb, const float* __restrict__ ub,
            __half* __restrict__ dst)
{
    constexpr int KT = (DINP + U) / 32, JH = U / (WAVES * 16);
    const int i = blockIdx.x * 256 + threadIdx.x;   // < 2*WAVES*JH*KT*2048
    const int jj   = i & 7;
    const int lane = (i >> 3) & 63;
    const int g    = (i >> 9) & 3;
    int rest = i >> 11;
    const int kt = rest % KT; rest /= KT;
    const int jh = rest % JH; rest /= JH;
    const int wv = rest % WAVES; rest /= WAVES;
    const int d  = rest;
    const int col = g * U + wv * (U / WAVES) + jh * 16 + (lane & 15);
    const int k   = kt * 32 + ((lane >> 4) << 3) + jj;
    const float* __restrict__ W  = d ? wb : wf;
    const float* __restrict__ Ur = d ? ub : uf;
    float v;
    if (k < DINS)      v = W[(size_t)k * (4 * U) + col];
    else if (k < DINP) v = 0.0f;
    else               v = Ur[(size_t)(k - DINP) * (4 * U) + col];
    dst[i] = __float2half(v);
}

// ---------------------------------------------------------------------------
// Pack d1w (15360,256) into per-(t,dir) B-fragment slabs for 8 waves:
//   [t 30][d 2][wv 8][kt 8][nt 2][lane 64][jj 8]
// n = wv*32 + nt*16 + (lane&15); k = kt*32 + (lane>>4)*8 + jj;
// element = d1w[(t*512 + d*256 + k)*256 + n].
// ---------------------------------------------------------------------------
__global__ __launch_bounds__(256)
void pack_d1(const float* __restrict__ src, __half* __restrict__ dst)
{
    const int i = blockIdx.x * 256 + threadIdx.x;   // < 3,932,160
    const int jj   = i & 7;
    const int lane = (i >> 3) & 63;
    const int nt   = (i >> 9) & 1;
    const int kt   = (i >> 10) & 7;
    const int wv   = (i >> 13) & 7;
    const int d    = (i >> 16) & 1;
    const int t    = i >> 17;
    const int n = wv * 32 + nt * 16 + (lane & 15);
    const int k = kt * 32 + ((lane >> 4) << 3) + jj;
    dst[i] = __float2half(src[(size_t)(t * 512 + d * 256 + k) * 256 + n]);
}

// ---------------------------------------------------------------------------
// MFMA bidirectional LSTM layer. Block = M=MT*16 batch rows x one direction,
// WAVES*64 threads, iterates all TT steps.
// Per step: Z[M][4U] = [x_t | h] @ [W;U] + b via 16x16x32 f16 MFMA.
// Wave wv owns hidden cols [wv*(U/WAVES), +U/WAVES) x all 4 gates; processed
// in JH passes of 16 hidden cols (4 gate n-tiles each) so the accumulator
// stays at MT*4 f32x4. B-fragments are disjoint across passes (no re-read);
// A-fragments re-read (x: L1-hot global, h: LDS).
// h (f16) in LDS, single buffer, 2 barriers/step. c (fp32) in VGPRs
// (C-layout row=quad*4+reg, col=lane&15).
// FUSE (lstm3): per-step rank-256 dense1 MFMA update (acc 32 VGPR),
// atomicAdd epilogue (2 contenders/element).
// ---------------------------------------------------------------------------
template<int DIN, int U, int WAVES, int MT, bool FUSE>
__global__ __launch_bounds__(WAVES * 64, 2)
void lstm_mfma(const __half* __restrict__ xin,    // (B,T,DIN) f16
               const __half* __restrict__ PB,     // packed weights
               const float* __restrict__ biasf, const float* __restrict__ biasb,
               __half* __restrict__ out,          // (B,T,2U) f16 (non-FUSE)
               const __half* __restrict__ PD1, float* __restrict__ d1o)
{
    constexpr int KT = (DIN + U) / 32, KTI = DIN / 32, KTR = KT - KTI;
    constexpr int JH = U / (WAVES * 16);
    constexpr int M  = MT * 16, HS = U + 8;
    constexpr int NTH = WAVES * 64;

    const int dir = blockIdx.y;
    const int tid = threadIdx.x;
    const int lane = tid & 63, wv = tid >> 6;
    const int l16 = lane & 15, quad = lane >> 4;
    const int row0 = blockIdx.x * M;
    const float* __restrict__ bias = dir ? biasb : biasf;

    __shared__ __align__(16) __half hbuf[M][HS];

    // bias regs for this wave's (jh, gate) columns
    float bg[JH][4];
#pragma unroll
    for (int jh = 0; jh < JH; ++jh)
#pragma unroll
        for (int g = 0; g < 4; ++g)
            bg[jh][g] = bias[g * U + wv * (U / WAVES) + jh * 16 + l16];

    float creg[MT][JH][4];
#pragma unroll
    for (int mt = 0; mt < MT; ++mt)
#pragma unroll
        for (int jh = 0; jh < JH; ++jh)
#pragma unroll
            for (int r = 0; r < 4; ++r) creg[mt][jh][r] = 0.0f;

    f32x4v acc1[FUSE ? MT : 1][FUSE ? 2 : 1];
#pragma unroll
    for (int mt = 0; mt < (FUSE ? MT : 1); ++mt)
#pragma unroll
        for (int nt = 0; nt < (FUSE ? 2 : 1); ++nt)
            acc1[mt][nt] = f32x4v{0.0f, 0.0f, 0.0f, 0.0f};

    for (int i = tid; i < M * HS; i += NTH) ((__half*)hbuf)[i] = __half(0.0f);

    // per-m-tile x row bases
    size_t xb[MT];
#pragma unroll
    for (int mt = 0; mt < MT; ++mt)
        xb[mt] = (size_t)(row0 + mt * 16 + l16) * TT * DIN;

    // wave's weight slab base: [dir][wv][jh][kt][g 4]*512
    const __half* __restrict__ PBw =
        PB + (size_t)((dir * WAVES + wv) * JH) * KT * 2048 + lane * 8;

    __syncthreads();

#pragma unroll 1
    for (int s = 0; s < TT; ++s) {
        const int t = dir ? (TT - 1 - s) : s;
        float hv[MT][JH][4];

#pragma unroll
        for (int jh = 0; jh < JH; ++jh) {
            const __half* __restrict__ PBj = PBw + (size_t)jh * KT * 2048;

            f32x4v acc[MT][4];
#pragma unroll
            for (int mt = 0; mt < MT; ++mt)
#pragma unroll
                for (int g = 0; g < 4; ++g)
                    acc[mt][g] = f32x4v{bg[jh][g], bg[jh][g], bg[jh][g], bg[jh][g]};

            // ---- input contribution (A from global x) ----
#pragma unroll
            for (int kt = 0; kt < KTI; ++kt) {
                f16x8v a[MT];
#pragma unroll
                for (int mt = 0; mt < MT; ++mt)
                    a[mt] = ldb16(xin + xb[mt] + (size_t)t * DIN + kt * 32 + quad * 8);
                const __half* bp = PBj + (size_t)kt * 2048;
#pragma unroll
                for (int g = 0; g < 4; ++g) {
                    const f16x8v b = ldb16(bp + g * 512);
#pragma unroll
                    for (int mt = 0; mt < MT; ++mt)
                        acc[mt][g] = mfma16(a[mt], b, acc[mt][g]);
                }
            }
            // ---- recurrent contribution (A from LDS h) ----
#pragma unroll
            for (int kt = 0; kt < KTR; ++kt) {
                f16x8v a[MT];
#pragma unroll
                for (int mt = 0; mt < MT; ++mt)
                    a[mt] = ldb16(&hbuf[mt * 16 + l16][kt * 32 + quad * 8]);
                const __half* bp = PBj + (size_t)(KTI + kt) * 2048;
#pragma unroll
                for (int g = 0; g < 4; ++g) {
                    const f16x8v b = ldb16(bp + g * 512);
#pragma unroll
                    for (int mt = 0; mt < MT; ++mt)
                        acc[mt][g] = mfma16(a[mt], b, acc[mt][g]);
                }
            }

            // ---- gates / state (C-layout: row=quad*4+r, col=l16) ----
#pragma unroll
            for (int mt = 0; mt < MT; ++mt)
#pragma unroll
                for (int r = 0; r < 4; ++r) {
                    const float zi = acc[mt][0][r];
                    const float zf = acc[mt][1][r];
                    const float zg = acc[mt][2][r];
                    const float zo = acc[mt][3][r];
                    const float cn = sigf(zf) * creg[mt][jh][r] + sigf(zi) * fmaxf(zg, 0.0f);
                    creg[mt][jh][r] = cn;
                    hv[mt][jh][r] = sigf(zo) * fmaxf(cn, 0.0f);
                }
        }

        __syncthreads();   // all reads of h(s-1) complete
#pragma unroll
        for (int mt = 0; mt < MT; ++mt)
#pragma unroll
            for (int jh = 0; jh < JH; ++jh)
#pragma unroll
                for (int r = 0; r < 4; ++r)
                    hbuf[mt * 16 + quad * 4 + r][wv * (U / WAVES) + jh * 16 + l16] =
                        __float2half(hv[mt][jh][r]);
        __syncthreads();   // h(s) visible

        if constexpr (FUSE) {
            // dense1 rank-256 update: acc1 += h_t @ d1w_slab(t,dir)
            const __half* slab = PD1 + (size_t)((t * 2 + dir) * WAVES + wv) * 8192 + lane * 8;
#pragma unroll
            for (int kt = 0; kt < 8; ++kt) {
                f16x8v a[MT];
#pragma unroll
                for (int mt = 0; mt < MT; ++mt)
                    a[mt] = ldb16(&hbuf[mt * 16 + l16][kt * 32 + quad * 8]);
#pragma unroll
                for (int nt = 0; nt < 2; ++nt) {
                    const f16x8v b = ldb16(slab + (kt * 2 + nt) * 512);
#pragma unroll
                    for (int mt = 0; mt < MT; ++mt)
                        acc1[mt][nt] = mfma16(a[mt], b, acc1[mt][nt]);
                }
            }
        } else {
            // coalesced h-out: (B,T,2U), this block's M rows, dir half
            constexpr int CH = U / 8;   // 16B chunks per row
            for (int i = tid; i < M * CH; i += NTH) {
                const int r = i / CH, cc = (i % CH) * 8;
                *(u32x4v*)(out + ((size_t)(row0 + r) * TT + t) * (2 * U) + dir * U + cc) =
                    *(const u32x4v*)&hbuf[r][cc];
            }
        }
    }

    if constexpr (FUSE) {
#pragma unroll
        for (int mt = 0; mt < MT; ++mt)
#pragma unroll
            for (int nt = 0; nt < 2; ++nt)
#pragma unroll
                for (int r = 0; r < 4; ++r)
                    atomicAdd(d1o + (size_t)(row0 + mt * 16 + quad * 4 + r) * 256 +
                                  wv * 32 + nt * 16 + l16,
                              acc1[mt][nt][r]);
    }
}

// ---------------------------------------------------------------------------
__global__ __launch_bounds__(256)
void zero_f4(float* __restrict__ p)
{
    const size_t i = ((size_t)blockIdx.x * 256 + threadIdx.x) * 4;
    *(float4*)(p + i) = float4{0.0f, 0.0f, 0.0f, 0.0f};
}

// ---------------------------------------------------------------------------
// Tail: relu(d1o+d1b) -> dense2(256->128) relu -> dense3(128->64) relu ->
// batchnorm -> logits(64->26) -> softmax. One block = 16 batch rows.
// ---------------------------------------------------------------------------
__global__ __launch_bounds__(256)
void tail_kernel(const float* __restrict__ a1g, const float* __restrict__ d1b,
                 const float* __restrict__ d2w, const float* __restrict__ d2b,
                 const float* __restrict__ d3w, const float* __restrict__ d3b,
                 const float* __restrict__ bng, const float* __restrict__ bnb,
                 const float* __restrict__ bnm, const float* __restrict__ bnv,
                 const float* __restrict__ ow,  const float* __restrict__ ob,
                 float* __restrict__ outp)
{
    const int tid = threadIdx.x;
    const int row0 = blockIdx.x * 16;

    __shared__ float A1[16][256];
    __shared__ float A2[16][128];
    __shared__ float A3[16][64];
    __shared__ float LG[16][26];

    for (int i = tid; i < 16 * 256; i += 256) {
        const int c = i & 255;
        A1[i >> 8][c] = fmaxf(a1g[(size_t)row0 * 256 + i] + d1b[c], 0.0f);
    }
    __syncthreads();

    { // dense2: 16x128 outputs, 8 per thread
        const int r = tid >> 4, j0 = (tid & 15) * 8;
        float acc[8];
#pragma unroll
        for (int q = 0; q < 8; ++q) acc[q] = d2b[j0 + q];
#pragma unroll 4
        for (int k = 0; k < 256; ++k) {
            const float av = A1[r][k];
            const float* wr = d2w + (size_t)k * 128 + j0;
            float w8[8];
            *(float4*)w8       = *(const float4*)wr;
            *(float4*)(w8 + 4) = *(const float4*)(wr + 4);
#pragma unroll
            for (int q = 0; q < 8; ++q) acc[q] = fmaf(av, w8[q], acc[q]);
        }
#pragma unroll
        for (int q = 0; q < 8; ++q) A2[r][j0 + q] = fmaxf(acc[q], 0.0f);
    }
    __syncthreads();

    { // dense3 + batchnorm
        const int r = tid >> 4, j0 = (tid & 15) * 4;
        float acc[4];
#pragma unroll
        for (int q = 0; q < 4; ++q) acc[q] = d3b[j0 + q];
#pragma unroll 4
        for (int k = 0; k < 128; ++k) {
            const float av = A2[r][k];
            float w4[4];
            *(float4*)w4 = *(const float4*)(d3w + (size_t)k * 64 + j0);
#pragma unroll
            for (int q = 0; q < 4; ++q) acc[q] = fmaf(av, w4[q], acc[q]);
        }
#pragma unroll
        for (int q = 0; q < 4; ++q) {
            const int jc = j0 + q;
            const float h = fmaxf(acc[q], 0.0f);
            const float sc = bng[jc] * rsqrtf(bnv[jc] + 0.001f);
            A3[r][jc] = (h - bnm[jc]) * sc + bnb[jc];
        }
    }
    __syncthreads();

    for (int i = tid; i < 16 * 26; i += 256) { // logits
        const int r = i / 26, jc = i % 26;
        float acc = ob[jc];
#pragma unroll 4
        for (int k = 0; k < 64; ++k) acc = fmaf(A3[r][k], ow[(size_t)k * 26 + jc], acc);
        LG[r][jc] = acc;
    }
    __syncthreads();

    if (tid < 16) { // softmax
        const int r = tid;
        float m = -1e30f;
        for (int c = 0; c < 26; ++c) m = fmaxf(m, LG[r][c]);
        float s = 0.0f;
        float e[26];
        for (int c = 0; c < 26; ++c) { e[c] = __expf(LG[r][c] - m); s += e[c]; }
        const float inv = 1.0f / s;
        for (int c = 0; c < 26; ++c)
            outp[(size_t)(row0 + r) * 26 + c] = e[c] * inv;
    }
}

// ---------------------------------------------------------------------------
extern "C" void kernel_launch(void* const* d_in, const int* in_sizes, int n_in,
                              void* d_out, int out_size, void* d_ws, size_t ws_size,
                              hipStream_t stream)
{
    const float* x   = (const float*)d_in[0];
    const float* w1f = (const float*)d_in[1];
    const float* u1f = (const float*)d_in[2];
    const float* b1f = (const float*)d_in[3];
    const float* w1b = (const float*)d_in[4];
    const float* u1b = (const float*)d_in[5];
    const float* b1b = (const float*)d_in[6];
    const float* w2f = (const float*)d_in[7];
    const float* u2f = (const float*)d_in[8];
    const float* b2f = (const float*)d_in[9];
    const float* w2b = (const float*)d_in[10];
    const float* u2b = (const float*)d_in[11];
    const float* b2b = (const float*)d_in[12];
    const float* w3f = (const float*)d_in[13];
    const float* u3f = (const float*)d_in[14];
    const float* b3f = (const float*)d_in[15];
    const float* w3b = (const float*)d_in[16];
    const float* u3b = (const float*)d_in[17];
    const float* b3b = (const float*)d_in[18];
    const float* d1w = (const float*)d_in[19];
    const float* d1b = (const float*)d_in[20];
    const float* d2w = (const float*)d_in[21];
    const float* d2b = (const float*)d_in[22];
    const float* d3w = (const float*)d_in[23];
    const float* d3b = (const float*)d_in[24];
    const float* bng = (const float*)d_in[25];
    const float* bnb = (const float*)d_in[26];
    const float* bnm = (const float*)d_in[27];
    const float* bnv = (const float*)d_in[28];
    const float* ow  = (const float*)d_in[29];
    const float* ob  = (const float*)d_in[30];

    // Workspace map (bytes). Proven safe footprint (R3/R4): 189,333,504.
    //   h1  f16 (B,T,128) @ 0            .. 62,914,560
    //   h2  f16 (B,T,256) @ 62,914,560   .. 188,743,680
    //     x16 f16 (B,T,128) @ 62,914,560  (dead before lstm2 writes h2)
    //     PB1 @ 125,829,120 (196,608 B)   (dead before lstm2 writes h2)
    //   PB2 @ 188,743,680 (524,288 B)    .. 189,267,968
    //   after lstm2, h1 region reused:
    //     d1o fp32 @ 0 (8,388,608 B)
    //     PD1 @ 8,388,608 (7,864,320 B)
    //     PB3 @ 16,252,928 (2,097,152 B) .. 18,350,080
    char* wsb = (char*)d_ws;
    __half* h1  = (__half*)wsb;
    __half* h2  = (__half*)(wsb + 62914560);
    __half* x16 = (__half*)(wsb + 62914560);
    __half* PB1 = (__half*)(wsb + 125829120);
    __half* PB2 = (__half*)(wsb + 188743680);
    float*  d1o = (float*)wsb;
    __half* PD1 = (__half*)(wsb + 8388608);
    __half* PB3 = (__half*)(wsb + 16252928);

    const dim3 blk(256);

    x_to_f16<<<dim3(122880), blk, 0, stream>>>(x, x16);
    pack_b<126, 128,  64, 4><<<dim3( 384), blk, 0, stream>>>(w1f, u1f, w1b, u1b, PB1);
    pack_b<128, 128, 128, 8><<<dim3(1024), blk, 0, stream>>>(w2f, u2f, w2b, u2b, PB2);

    // lstm1: U=64, M=32, 4 waves, 512 blocks (2/CU)
    lstm_mfma<128,  64, 4, 2, false><<<dim3(BATCH / 32, 2), dim3(256), 0, stream>>>(
        x16, PB1, b1f, b1b, h1, nullptr, nullptr);
    // lstm2: U=128, M=64, 8 waves, 256 blocks (1/CU)
    lstm_mfma<128, 128, 8, 4, false><<<dim3(BATCH / 64, 2), dim3(512), 0, stream>>>(
        h1, PB2, b2f, b2b, h2, nullptr, nullptr);

    // h1 dead: carve d1o, PD1, PB3 out of its region
    zero_f4<<<dim3(2048), blk, 0, stream>>>(d1o);
    pack_b<256, 256, 256, 8><<<dim3(4096), blk, 0, stream>>>(w3f, u3f, w3b, u3b, PB3);
    pack_d1<<<dim3(15360), blk, 0, stream>>>(d1w, PD1);

    // lstm3: U=256, M=64, 8 waves, 256 blocks (1/CU), fused dense1
    lstm_mfma<256, 256, 8, 4, true><<<dim3(BATCH / 64, 2), dim3(512), 0, stream>>>(
        h2, PB3, b3f, b3b, nullptr, PD1, d1o);

    tail_kernel<<<dim3(BATCH / 16), blk, 0, stream>>>(
        d1o, d1b, d2w, d2b, d3w, d3b, bng, bnb, bnm, bnv, ow, ob, (float*)d_out);
}